// Round 17
// baseline (66.524 us; speedup 1.0000x reference)
//
#include <hip/hip_runtime.h>

#define NS 512
#define DM 512
#define NH 8
#define DH 64
#define ATTN_SIZE (2 * NH * NS * NS)  // 4194304

typedef __attribute__((ext_vector_type(8))) _Float16 half8;
typedef __attribute__((ext_vector_type(4))) float f32x4;
typedef _Float16 h2 __attribute__((ext_vector_type(2)));
typedef unsigned short ushort_t;
typedef __attribute__((ext_vector_type(2))) unsigned uint2v;

#if defined(__has_builtin)
#if __has_builtin(__builtin_amdgcn_fdot2)
#define HAVE_FDOT2 1
#endif
#if __has_builtin(__builtin_amdgcn_cvt_pkrtz)
#define HAVE_PKRTZ 1
#endif
#endif

__device__ __forceinline__ unsigned pkh(float a, float b) {
#ifdef HAVE_PKRTZ
    auto r = __builtin_amdgcn_cvt_pkrtz(a, b);   // __fp16 ext_vector(2)
    return __builtin_bit_cast(unsigned, r);
#else
    h2 r; r[0] = (_Float16)a; r[1] = (_Float16)b;
    return __builtin_bit_cast(unsigned, r);
#endif
}

__device__ __forceinline__ float qdot2(unsigned w2, unsigned x2, float acc) {
#ifdef HAVE_FDOT2
    return __builtin_amdgcn_fdot2(__builtin_bit_cast(h2, w2),
                                  __builtin_bit_cast(h2, x2), acc, false);
#else
    h2 a = __builtin_bit_cast(h2, w2);
    h2 b = __builtin_bit_cast(h2, x2);
    return acc + (float)a[0] * (float)b[0] + (float)a[1] * (float)b[1];
#endif
}

__device__ __forceinline__ float dotabs(unsigned w2, unsigned q2, unsigned k2, float acc) {
    h2 s = __builtin_bit_cast(h2, q2) + __builtin_bit_cast(h2, k2);  // v_pk_add_f16
    unsigned a = __builtin_bit_cast(unsigned, s) & 0x7FFF7FFFu;      // packed |.|
    return qdot2(w2, a, acc);                                        // v_dot2_f32_f16
}

// ---------------------------------------------------------------------------
// ONE kernel, NO grid barrier (poll-loop fusion kills codegen; fused6 proved
// barrier-free correct at VGPR=128). 512 blocks = (kt:4) x (bh:16) x (qt:8).
// fused6 structure with the staging latency hidden:
//  - Bq AND Bk resident in LDS per K-chunk; W REGISTER-PREFETCHED one chunk
//    ahead (no exposed W latency).
//  - A (query) staged per 64-row group through LDS (coalesced, fused6
//    pattern); loads issue at round start, overlapped by B-writes/MFMA.
//  - 12 A-rounds + 4 B-writes (vs fused6's 24 mixed rounds).
// Phase C attn core + epilogue verbatim from fused6 (verified).
// ---------------------------------------------------------------------------
__global__ __attribute__((amdgpu_flat_work_group_size(256, 256),
                          amdgpu_waves_per_eu(2, 4)))
void fused9(const float* __restrict__ query,
            const float* __restrict__ Wq, const float* __restrict__ bq,
            const float* __restrict__ Wk, const float* __restrict__ bk,
            const float* __restrict__ w,
            float* __restrict__ kout, float* __restrict__ attn)
{
    __shared__ __align__(16) char smem[52224];
    // phase A: Bq[64][136] @0, Bk[64][136] @17408, As[64][136] @34816
    // phase C overlay: Qt[64][72] @0 (9216 B), Kt[128][72] @9216 (18432 B)
    ushort_t (*Bq)[136] = (ushort_t(*)[136])smem;
    ushort_t (*Bk)[136] = (ushort_t(*)[136])(smem + 17408);
    ushort_t (*As)[136] = (ushort_t(*)[136])(smem + 34816);
    ushort_t (*Qt)[72]  = (ushort_t(*)[72])smem;
    ushort_t (*Kt)[72]  = (ushort_t(*)[72])(smem + 9216);

    const int tid  = threadIdx.x;
    const int bid  = blockIdx.x;
    const int kt   = bid & 3;          // 128 k-cols
    const int bh   = (bid >> 2) & 15;  // b*8+h
    const int qt   = bid >> 6;         // 0..7 (64 q-rows)
    const int b    = bh >> 3;
    const int h    = bh & 7;

    const int lane = tid & 63;
    const int w4   = tid >> 6;         // wave 0..3
    const int l15  = lane & 15, l4 = lane >> 4;

    // =================== Phase A: projections (f16 MFMA) ===================
    f32x4 acc[3][4];
    #pragma unroll
    for (int g = 0; g < 3; ++g)
        #pragma unroll
        for (int cf = 0; cf < 4; ++cf) acc[g][cf] = (f32x4){0.f, 0.f, 0.f, 0.f};

    const int nsb[3] = {qt * 64, kt * 128, kt * 128 + 64};

    // W prefetch buffers (one K-chunk ahead): 32 f32 each
    float wqr[8][4], wkr[8][4];
    #pragma unroll
    for (int p = 0; p < 8; ++p)
        #pragma unroll
        for (int j = 0; j < 4; ++j) {
            const size_t off = (size_t)(p * 16 + w4 * 4 + j) * (NH * DH) + h * 64 + lane;
            wqr[p][j] = Wq[off];
            wkr[p][j] = Wk[off];
        }

    for (int kc = 0; kc < 4; ++kc) {
        // ---- round 0: stage B panels (from regs) + As(g0), MFMA g0 ----
        __syncthreads();   // previous round's As/B readers done
        {   // As group 0 (fused6 pattern, coalesced)
            const int base = nsb[0];
            #pragma unroll
            for (int i = 0; i < 4; ++i) {
                int s = i * 256 + tid;
                int r = s >> 4, q8 = s & 15;
                const float* src = query + (size_t)(2 * (base + r) + b) * DM
                                 + kc * 128 + q8 * 8;
                float4 v0 = *(const float4*)(src);
                float4 v1 = *(const float4*)(src + 4);
                uint4 pk;
                pk.x = pkh(v0.x, v0.y);
                pk.y = pkh(v0.z, v0.w);
                pk.z = pkh(v1.x, v1.y);
                pk.w = pkh(v1.z, v1.w);
                *(uint4*)&As[r][q8 * 8] = pk;
            }
        }
        #pragma unroll
        for (int p = 0; p < 8; ++p) {   // B panels from prefetched regs
            uint2v pka, pkb;
            pka.x = pkh(wqr[p][0], wqr[p][1]);
            pka.y = pkh(wqr[p][2], wqr[p][3]);
            pkb.x = pkh(wkr[p][0], wkr[p][1]);
            pkb.y = pkh(wkr[p][2], wkr[p][3]);
            *(uint2v*)&Bq[lane][p * 16 + w4 * 4] = pka;
            *(uint2v*)&Bk[lane][p * 16 + w4 * 4] = pkb;
        }
        if (kc < 3) {   // prefetch next chunk's W panels
            #pragma unroll
            for (int p = 0; p < 8; ++p)
                #pragma unroll
                for (int j = 0; j < 4; ++j) {
                    const size_t off = (size_t)((kc + 1) * 128 + p * 16 + w4 * 4 + j)
                                     * (NH * DH) + h * 64 + lane;
                    wqr[p][j] = Wq[off];
                    wkr[p][j] = Wk[off];
                }
        }
        __syncthreads();
        #pragma unroll
        for (int cf = 0; cf < 4; ++cf)
            #pragma unroll
            for (int ks = 0; ks < 4; ++ks)
                acc[0][cf] = __builtin_amdgcn_mfma_f32_16x16x32_f16(
                    *(const half8*)&As[w4 * 16 + l15][ks * 32 + l4 * 8],
                    *(const half8*)&Bq[cf * 16 + l15][ks * 32 + l4 * 8],
                    acc[0][cf], 0, 0, 0);

        // ---- rounds 1,2: As(g), MFMA g with Bk ----
        #pragma unroll
        for (int g = 1; g < 3; ++g) {
            __syncthreads();
            const int base = nsb[g];
            #pragma unroll
            for (int i = 0; i < 4; ++i) {
                int s = i * 256 + tid;
                int r = s >> 4, q8 = s & 15;
                const float* src = query + (size_t)(2 * (base + r) + b) * DM
                                 + kc * 128 + q8 * 8;
                float4 v0 = *(const float4*)(src);
                float4 v1 = *(const float4*)(src + 4);
                uint4 pk;
                pk.x = pkh(v0.x, v0.y);
                pk.y = pkh(v0.z, v0.w);
                pk.z = pkh(v1.x, v1.y);
                pk.w = pkh(v1.z, v1.w);
                *(uint4*)&As[r][q8 * 8] = pk;
            }
            __syncthreads();
            #pragma unroll
            for (int cf = 0; cf < 4; ++cf)
                #pragma unroll
                for (int ks = 0; ks < 4; ++ks)
                    acc[g][cf] = __builtin_amdgcn_mfma_f32_16x16x32_f16(
                        *(const half8*)&As[w4 * 16 + l15][ks * 32 + l4 * 8],
                        *(const half8*)&Bk[cf * 16 + l15][ks * 32 + l4 * 8],
                        acc[g][cf], 0, 0, 0);
        }
    }

    // ============ epilogue -> LDS tiles (+ kout for qt==0) [fused6] ============
    __syncthreads();   // all MFMA reads done; overlay becomes Qt/Kt
    #pragma unroll
    for (int g = 0; g < 3; ++g) {
        const float* __restrict__ bia = g ? bk : bq;
        #pragma unroll
        for (int cf = 0; cf < 4; ++cf) {
            const int col = cf * 16 + l15;
            const float bg = bia[h * 64 + col];
            #pragma unroll
            for (int j = 0; j < 4; ++j) {
                const int rloc = w4 * 16 + l4 * 4 + j;
                float v = acc[g][cf][j] + bg;
                _Float16 hv = (_Float16)v;
                if (g == 0) {
                    Qt[rloc][col] = __builtin_bit_cast(ushort_t, hv);
                } else {
                    Kt[(g - 1) * 64 + rloc][col] = __builtin_bit_cast(ushort_t, hv);
                    if (qt == 0)
                        kout[((size_t)(b * NH + h) * NS + kt * 128 + (g - 1) * 64 + rloc) * DH + col] = v;
                }
            }
        }
    }
    __syncthreads();   // tiles visible to all waves

    // =================== Phase C: attn core (fused6 verbatim) ===================
    __align__(16) unsigned kr0[32], kr1[32];
    #pragma unroll
    for (int i = 0; i < 8; ++i)
        *(uint4*)&kr0[i * 4] = *(const uint4*)&Kt[lane][i * 8];
    #pragma unroll
    for (int i = 0; i < 8; ++i)
        *(uint4*)&kr1[i * 4] = *(const uint4*)&Kt[64 + lane][i * 8];

    unsigned wp[32];
    const float* wrow = w + h * DH;
    #pragma unroll
    for (int i = 0; i < 16; ++i) {
        float4 v = *(const float4*)(wrow + i * 4);
        wp[2 * i]     = (unsigned)__builtin_amdgcn_readfirstlane((int)pkh(v.x, v.y));
        wp[2 * i + 1] = (unsigned)__builtin_amdgcn_readfirstlane((int)pkh(v.z, v.w));
    }

    float kd0 = 0.f, kd1 = 0.f;
    #pragma unroll
    for (int p = 0; p < 32; ++p) {
        kd0 = qdot2(wp[p], kr0[p], kd0);
        kd1 = qdot2(wp[p], kr1[p], kd1);
    }

    #pragma unroll
    for (int t = 0; t < 2; ++t) {
        float* obase = attn + (size_t)bh * NS * NS
                     + (size_t)(qt * 64 + t * 32 + w4 * 8) * NS + kt * 128 + lane;
        #pragma unroll 2
        for (int r = 0; r < 8; ++r) {
            const int row = t * 32 + w4 * 8 + r;
            __align__(16) unsigned q2a[32];
            #pragma unroll
            for (int i = 0; i < 8; ++i)
                *(uint4*)&q2a[i * 4] = *(const uint4*)&Qt[row][i * 8];

            float qd0 = 0.f, qd1 = 0.f;
            #pragma unroll
            for (int p = 0; p < 16; ++p) {
                qd0 = qdot2(wp[2 * p],     q2a[2 * p],     qd0);
                qd1 = qdot2(wp[2 * p + 1], q2a[2 * p + 1], qd1);
            }
            const float qd = qd0 + qd1;

            float a0 = 0.f, a1 = 0.f;
            #pragma unroll
            for (int p = 0; p < 32; ++p) {
                const unsigned q2 = q2a[p], w2 = wp[p];
                a0 = dotabs(w2, q2, kr0[p], a0);
                a1 = dotabs(w2, q2, kr1[p], a1);
            }

            float* ob = obase + r * NS;
            ob[0]  = fmaf(0.495f, a0, 0.505f * (qd + kd0));
            ob[64] = fmaf(0.495f, a1, 0.505f * (qd + kd1));
        }
    }
}

extern "C" void kernel_launch(void* const* d_in, const int* in_sizes, int n_in,
                              void* d_out, int out_size, void* d_ws, size_t ws_size,
                              hipStream_t stream) {
    const float* query = (const float*)d_in[0];
    const float* Wq    = (const float*)d_in[1];
    const float* bq    = (const float*)d_in[2];
    const float* Wk    = (const float*)d_in[3];
    const float* bk    = (const float*)d_in[4];
    const float* w     = (const float*)d_in[5];

    float* attn = (float*)d_out;
    float* kout = (float*)d_out + ATTN_SIZE;     // k-proj f32 == output 2

    fused9<<<dim3(512), dim3(256), 0, stream>>>(query, Wq, bq, Wk, bk, w,
                                                kout, attn);
}